// Round 2
// baseline (4933.994 us; speedup 1.0000x reference)
//
#include <hip/hip_runtime.h>

// SubLSTM: G=8 groups, D=20 hidden, B=64, T=2000, F=160.
// Zero-workspace pipeline:
//   scan0: x --(fused Wih0@x + LSTM layer0)--> d_out holds h0 in [b][t][g*20+d]
//   scan1: d_out --(fused Wih1@h0 + LSTM layer1, IN PLACE)--> d_out = fullband (+x residual)
//   mlp:   d_out = relu(d_out@W1.T+b1)@W2.T + b2, in place.
// In-place safety of scan1: each wave reads h0[t+PF] (prefetch) strictly before
// it writes fullband[t] at the same addresses (PF steps later, same program order);
// chains touch disjoint address sets. d_ws is NOT used.

#define Gn 8
#define Dn 20
#define Bn 64
#define Tn 2000
#define Fn 160
#define NR (Bn * Tn)  // 128000 rows
#define PF 8          // scan prefetch depth

__device__ __forceinline__ float fsigm(float x) {
  return __builtin_amdgcn_rcpf(1.f + __expf(-x));
}
__device__ __forceinline__ float ftanh(float x) {
  // tanh(x) = 1 - 2/(exp(2x)+1); exp overflow -> rcp(inf)=0 -> 1 (safe)
  return 1.f - 2.f * __builtin_amdgcn_rcpf(__expf(2.f * x) + 1.f);
}
__device__ __forceinline__ float rdlane(float v, int k) {
  return __int_as_float(__builtin_amdgcn_readlane(__float_as_int(v), k));
}

// One wave per (g,b) chain. Lane j owns gate j (lanes 0..15 also own gate 64+j).
// Wih and Whh rows live in VGPRs; x_t and h broadcast via v_readlane.
// in:  read x_t[d] at in[(b*T+t)*F + g*20 + d]   (x for layer0, h0-in-dout for layer1)
// out: write h (+ residual if mode==1) at out[(b*T+t)*F + g*20 + d]
__global__ __launch_bounds__(64) void scan_fused_kernel(
    const float* __restrict__ in, const float* __restrict__ Wih,
    const float* __restrict__ Whh, const float* __restrict__ bih,
    const float* __restrict__ bhh, const float* __restrict__ res,
    float* __restrict__ out, const int mode) {
  const int lane = threadIdx.x;
  const int chain = blockIdx.x;  // 0..511
  const int g = chain >> 6;
  const int b = chain & 63;
  const float* Wg = Whh + g * 1600;
  const float* Ug = Wih + g * 1600;
  float WA[20], WB[20], UA[20], UB[20];
  {
    const int rB = 64 + (lane & 15);  // rows 64..79 (dup on lanes>=16, unused there)
#pragma unroll
    for (int k = 0; k < 20; ++k) {
      WA[k] = Wg[lane * 20 + k];
      WB[k] = Wg[rB * 20 + k];
      UA[k] = Ug[lane * 20 + k];
      UB[k] = Ug[rB * 20 + k];
    }
  }
  const float bsA = bih[g * 80 + lane] + bhh[g * 80 + lane];
  const float bsB = bih[g * 80 + 64 + (lane & 15)] + bhh[g * 80 + 64 + (lane & 15)];
  const bool wl = lane < Dn;
  const long long base = ((long long)b * Tn) * Fn + g * Dn;
  const float* inp = in + base;
  const float* resp = res + base;
  float* outp = out + base + (wl ? lane : 0);

  float px[PF], pr[PF];
#pragma unroll
  for (int p = 0; p < PF; ++p) {
    px[p] = wl ? inp[(long long)p * Fn + lane] : 0.f;
    pr[p] = (mode && wl) ? resp[(long long)p * Fn + lane] : 0.f;
  }

  float h = 0.f, c = 0.f;
  for (int t0 = 0; t0 < Tn; t0 += PF) {
#pragma unroll
    for (int p = 0; p < PF; ++p) {
      const int t = t0 + p;
      const float xv = px[p];
      const float rv = pr[p];
      const int tp = t + PF;
      if (tp < Tn) {  // prefetch PF steps ahead (hide HBM latency; off critical chain)
        px[p] = wl ? inp[(long long)tp * Fn + lane] : 0.f;
        if (mode) pr[p] = wl ? resp[(long long)tp * Fn + lane] : 0.f;
      }
      // gates = b + Wih@x_t + Whh@h ; x_t,h broadcast from lanes 0..19
      float a0 = bsA, a1 = 0.f, c0 = bsB, c1 = 0.f;
#pragma unroll
      for (int k = 0; k < 20; k += 2) {
        const float hk0 = rdlane(h, k);
        const float hk1 = rdlane(h, k + 1);
        const float xk0 = rdlane(xv, k);
        const float xk1 = rdlane(xv, k + 1);
        a0 += WA[k] * hk0 + UA[k] * xk0;
        a1 += WA[k + 1] * hk1 + UA[k + 1] * xk1;
        c0 += WB[k] * hk0 + UB[k] * xk0;
        c1 += WB[k + 1] * hk1 + UB[k + 1] * xk1;
      }
      const float gA = a0 + a1;  // gates[lane], lanes 0..63
      const float gB = c0 + c1;  // gates[64+(lane&15)], lanes 0..15 valid
      // gather i,f,g,o for update lanes k=0..19 (PyTorch gate order i,f,g,o):
      // i_k = gates[k] (resident); f_k = gates[20+k]; g_k = gates[40+k];
      // o_k = gates[60+k] -> gA@(60+k) for k<4 else gB@(k-4)
      const float fg = __shfl(gA, (20 + lane) & 63);
      const float gg = __shfl(gA, (40 + lane) & 63);
      const float o1v = __shfl(gA, (60 + lane) & 63);
      const float o2v = __shfl(gB, (lane - 4) & 63);
      const float og = (lane < 4) ? o1v : o2v;
      const float sI = fsigm(gA);
      const float sF = fsigm(fg);
      const float sO = fsigm(og);
      const float tG = ftanh(gg);
      c = sF * c + sI * tG;
      h = sO * ftanh(c);
      if (wl) outp[(long long)t * Fn] = h + rv;
    }
  }
}

// Fused MLP, in-place on io[NR][160]: io = relu(io@W1.T + b1)@W2.T + b2.
// Block: 32-row tile, 256 threads, per-thread 2x10 output micro-tile.
#define LDF 164  // 160 + 4 pad (float4-aligned, 2-way-max banks)
__global__ __launch_bounds__(256) void mlp_kernel(
    float* __restrict__ io, const float* __restrict__ W1,
    const float* __restrict__ b1, const float* __restrict__ W2,
    const float* __restrict__ b2) {
  __shared__ float FBs[32 * LDF];  // 21.0 KB input tile
  __shared__ float W1s[16 * LDF];  // 10.5 KB W1 chunk
  __shared__ float Hs[32 * 17];    //  2.2 KB relu(h) chunk
  __shared__ float W2s[160 * 17];  // 10.9 KB W2 chunk (transposed)
  const int tid = threadIdx.x;
  const long long r0 = (long long)blockIdx.x * 32;
  {  // stage FB tile: 32x160 contiguous floats
    const float4* src = (const float4*)(io + r0 * Fn);
    for (int v = tid; v < 1280; v += 256) {
      const int r = v / 40, pz = v % 40;
      *(float4*)&FBs[r * LDF + pz * 4] = src[v];
    }
  }
  float acc[2][10];
#pragma unroll
  for (int r = 0; r < 2; ++r)
#pragma unroll
    for (int cc = 0; cc < 10; ++cc) acc[r][cc] = 0.f;
  const int hrow = tid >> 3;      // 0..31
  const int hj0 = (tid & 7) * 2;  // 0..14
  const int tr = tid >> 4;        // 0..15 -> rows tr*2..+1
  const int tc = tid & 15;        // 0..15 -> cols tc*10..+9
  for (int jc = 0; jc < 640; jc += 16) {
    __syncthreads();  // prior-iter Hs/W2s reads done; FB stage done (iter 0)
    for (int v = tid; v < 640; v += 256) {
      const int r = v / 40, pz = v % 40;
      *(float4*)&W1s[r * LDF + pz * 4] =
          *(const float4*)(W1 + (long long)(jc + r) * Fn + pz * 4);
    }
    for (int v = tid; v < 2560; v += 256) {
      const int col = v >> 4, jj = v & 15;
      W2s[col * 17 + jj] = W2[col * 640 + jc + jj];
    }
    __syncthreads();
    // h chunk: each thread 2 dots of 160
    float hv0 = b1[jc + hj0], hv1 = b1[jc + hj0 + 1];
#pragma unroll
    for (int k = 0; k < 160; k += 4) {
      const float4 xf = *(const float4*)&FBs[hrow * LDF + k];
      const float4 w0 = *(const float4*)&W1s[hj0 * LDF + k];
      const float4 w1 = *(const float4*)&W1s[(hj0 + 1) * LDF + k];
      hv0 += xf.x * w0.x + xf.y * w0.y + xf.z * w0.z + xf.w * w0.w;
      hv1 += xf.x * w1.x + xf.y * w1.y + xf.z * w1.z + xf.w * w1.w;
    }
    Hs[hrow * 17 + hj0] = fmaxf(hv0, 0.f);
    Hs[hrow * 17 + hj0 + 1] = fmaxf(hv1, 0.f);
    __syncthreads();  // Hs visible to all before accumulate (was MISSING: race)
    // accumulate out tile
#pragma unroll
    for (int jj = 0; jj < 16; ++jj) {
      const float h0v = Hs[(tr * 2 + 0) * 17 + jj];
      const float h1v = Hs[(tr * 2 + 1) * 17 + jj];
#pragma unroll
      for (int cc = 0; cc < 10; ++cc) {
        const float w = W2s[(tc * 10 + cc) * 17 + jj];
        acc[0][cc] += h0v * w;
        acc[1][cc] += h1v * w;
      }
    }
  }
#pragma unroll
  for (int r = 0; r < 2; ++r) {
    float* orow = io + (r0 + tr * 2 + r) * Fn + tc * 10;
#pragma unroll
    for (int cc = 0; cc < 10; ++cc) orow[cc] = acc[r][cc] + b2[tc * 10 + cc];
  }
}

extern "C" void kernel_launch(void* const* d_in, const int* in_sizes, int n_in,
                              void* d_out, int out_size, void* d_ws, size_t ws_size,
                              hipStream_t stream) {
  const float* x    = (const float*)d_in[0];
  const float* Wih0 = (const float*)d_in[1];
  const float* Whh0 = (const float*)d_in[2];
  const float* bih0 = (const float*)d_in[3];
  const float* bhh0 = (const float*)d_in[4];
  const float* Wih1 = (const float*)d_in[5];
  const float* Whh1 = (const float*)d_in[6];
  const float* bih1 = (const float*)d_in[7];
  const float* bhh1 = (const float*)d_in[8];
  const float* W1   = (const float*)d_in[9];
  const float* b1   = (const float*)d_in[10];
  const float* W2   = (const float*)d_in[11];
  const float* b2   = (const float*)d_in[12];
  float* out = (float*)d_out;
  (void)d_ws; (void)ws_size;  // zero-workspace pipeline

  // Layer 0: x -> h0 staged in d_out ([b][t][g*20+d])
  scan_fused_kernel<<<dim3(512), dim3(64), 0, stream>>>(x, Wih0, Whh0, bih0, bhh0, x, out, 0);
  // Layer 1: d_out(h0) -> d_out(fullband = h1 + x residual), in place
  scan_fused_kernel<<<dim3(512), dim3(64), 0, stream>>>(out, Wih1, Whh1, bih1, bhh1, x, out, 1);
  // MLP in place on d_out
  mlp_kernel<<<dim3(4000), dim3(256), 0, stream>>>(out, W1, b1, W2, b2);
}

// Round 3
// 1663.190 us; speedup vs baseline: 2.9666x; 2.9666x over previous
//
#include <hip/hip_runtime.h>

// SubLSTM: G=8, D=20, B=64, T=2000, F=160.
// R3 pipeline (2 kernels, zero workspace):
//   scan2: both LSTM layers fused, one wave per (g,b) chain; layer1 input = layer0
//          h_t in registers (no h0 round-trip); writes fullband = h1 + x to d_out.
//   mlp_mfma: bf16 MFMA fused MLP, in-place on d_out (64-row tiles).
// MFMA layouts (m89-verified): A/B frag: idx=lane&15, k=(lane>>4)*8+j (8 bf16, b128);
// C/D: col=lane&15, row=(lane>>4)*4+reg.

#define Gn 8
#define Dn 20
#define Bn 64
#define Tn 2000
#define Fn 160
#define NR (Bn * Tn)  // 128000 rows
#define PFs 4         // scan prefetch ring depth

__device__ __forceinline__ float fsigm(float x) {
  return __builtin_amdgcn_rcpf(1.f + __expf(-x));
}
__device__ __forceinline__ float ftanh(float x) {
  return 1.f - 2.f * __builtin_amdgcn_rcpf(__expf(2.f * x) + 1.f);
}
__device__ __forceinline__ float rdlane(float v, int k) {
  return __int_as_float(__builtin_amdgcn_readlane(__float_as_int(v), k));
}
// Round-to-nearest fp32->bf16 (bit pattern in ushort)
__device__ __forceinline__ unsigned short f2bf(float f) {
  unsigned u = __float_as_uint(f);
  u += 0x8000u;
  return (unsigned short)(u >> 16);
}

// Gate gather + LSTM cell update (round-2-proven logic).
// gA = gates[lane] (0..63), gB = gates[64+(lane&15)] (valid lanes 0..15).
// Update lanes k=0..19: i=g[k], f=g[20+k], g=g[40+k], o=g[60+k].
__device__ __forceinline__ void lstm_update(float gA, float gB, int lane,
                                            float& h, float& c) {
  const float fg = __shfl(gA, (20 + lane) & 63);
  const float gg = __shfl(gA, (40 + lane) & 63);
  const float o1v = __shfl(gA, (60 + lane) & 63);
  const float o2v = __shfl(gB, (lane - 4) & 63);
  const float og = (lane < 4) ? o1v : o2v;
  const float sI = fsigm(gA);
  const float sF = fsigm(fg);
  const float sO = fsigm(og);
  const float tG = ftanh(gg);
  c = sF * c + sI * tG;
  h = sO * ftanh(c);
}

// Both layers fused. One wave per (g,b) chain; 512 blocks x 64.
__global__ __launch_bounds__(64) void scan2_kernel(
    const float* __restrict__ x, const float* __restrict__ Wih0,
    const float* __restrict__ Whh0, const float* __restrict__ bih0,
    const float* __restrict__ bhh0, const float* __restrict__ Wih1,
    const float* __restrict__ Whh1, const float* __restrict__ bih1,
    const float* __restrict__ bhh1, float* __restrict__ out) {
  const int lane = threadIdx.x;
  const int chain = blockIdx.x;
  const int g = chain >> 6;
  const int b = chain & 63;
  float W0A[20], W0B[20], U0A[20], U0B[20];
  float W1A[20], W1B[20], U1A[20], U1B[20];
  {
    const float* w0 = Whh0 + g * 1600;
    const float* u0 = Wih0 + g * 1600;
    const float* w1 = Whh1 + g * 1600;
    const float* u1 = Wih1 + g * 1600;
    const int rB = 64 + (lane & 15);
#pragma unroll
    for (int k = 0; k < 20; ++k) {
      W0A[k] = w0[lane * 20 + k];
      W0B[k] = w0[rB * 20 + k];
      U0A[k] = u0[lane * 20 + k];
      U0B[k] = u0[rB * 20 + k];
      W1A[k] = w1[lane * 20 + k];
      W1B[k] = w1[rB * 20 + k];
      U1A[k] = u1[lane * 20 + k];
      U1B[k] = u1[rB * 20 + k];
    }
  }
  const float bs0A = bih0[g * 80 + lane] + bhh0[g * 80 + lane];
  const float bs0B = bih0[g * 80 + 64 + (lane & 15)] + bhh0[g * 80 + 64 + (lane & 15)];
  const float bs1A = bih1[g * 80 + lane] + bhh1[g * 80 + lane];
  const float bs1B = bih1[g * 80 + 64 + (lane & 15)] + bhh1[g * 80 + 64 + (lane & 15)];
  const bool wl = lane < Dn;
  const long long base = ((long long)b * Tn) * Fn + g * Dn;
  const float* xpL = x + base + (wl ? lane : 0);
  float* outp = out + base + (wl ? lane : 0);

  float px[PFs];
#pragma unroll
  for (int p = 0; p < PFs; ++p) px[p] = xpL[(long long)p * Fn];

  float h0 = 0.f, c0 = 0.f, h1 = 0.f, c1 = 0.f;

#define STEP(t, p, PREF)                                                     \
  do {                                                                       \
    const float xv = px[p];                                                  \
    if (PREF) px[p] = xpL[(long long)((t) + PFs) * Fn];                      \
    /* layer 0: gates = b + U0@x + W0@h0 */                                  \
    float aH0 = bs0A, aH1 = 0.f, aX0 = 0.f, aX1 = 0.f;                       \
    float bH0 = bs0B, bH1 = 0.f, bX0 = 0.f, bX1 = 0.f;                       \
    _Pragma("unroll") for (int k = 0; k < 20; k += 2) {                      \
      const float hk0 = rdlane(h0, k), hk1 = rdlane(h0, k + 1);              \
      const float xk0 = rdlane(xv, k), xk1 = rdlane(xv, k + 1);              \
      aH0 += W0A[k] * hk0;                                                   \
      aH1 += W0A[k + 1] * hk1;                                               \
      aX0 += U0A[k] * xk0;                                                   \
      aX1 += U0A[k + 1] * xk1;                                               \
      bH0 += W0B[k] * hk0;                                                   \
      bH1 += W0B[k + 1] * hk1;                                               \
      bX0 += U0B[k] * xk0;                                                   \
      bX1 += U0B[k + 1] * xk1;                                               \
    }                                                                        \
    lstm_update((aH0 + aH1) + (aX0 + aX1), (bH0 + bH1) + (bX0 + bX1), lane,  \
                h0, c0);                                                     \
    /* layer 1: x-input = fresh h0 */                                        \
    float dH0 = bs1A, dH1 = 0.f, dX0 = 0.f, dX1 = 0.f;                       \
    float eH0 = bs1B, eH1 = 0.f, eX0 = 0.f, eX1 = 0.f;                       \
    _Pragma("unroll") for (int k = 0; k < 20; k += 2) {                      \
      const float hk0 = rdlane(h1, k), hk1 = rdlane(h1, k + 1);              \
      const float yk0 = rdlane(h0, k), yk1 = rdlane(h0, k + 1);              \
      dH0 += W1A[k] * hk0;                                                   \
      dH1 += W1A[k + 1] * hk1;                                               \
      dX0 += U1A[k] * yk0;                                                   \
      dX1 += U1A[k + 1] * yk1;                                               \
      eH0 += W1B[k] * hk0;                                                   \
      eH1 += W1B[k + 1] * hk1;                                               \
      eX0 += U1B[k] * yk0;                                                   \
      eX1 += U1B[k + 1] * yk1;                                               \
    }                                                                        \
    lstm_update((dH0 + dH1) + (dX0 + dX1), (eH0 + eH1) + (eX0 + eX1), lane,  \
                h1, c1);                                                     \
    if (wl) outp[(long long)(t) * Fn] = h1 + xv;                             \
  } while (0)

  for (int t0 = 0; t0 + PFs < Tn; t0 += PFs) {
#pragma unroll
    for (int p = 0; p < PFs; ++p) STEP(t0 + p, p, true);
  }
#pragma unroll
  for (int p = 0; p < PFs; ++p) STEP(Tn - PFs + p, p, false);
#undef STEP
}

// ---- MFMA bf16 MLP, in place on io[NR][160] ----
typedef __attribute__((ext_vector_type(8))) short bf16x8;
typedef __attribute__((ext_vector_type(4))) float f32x4;

// Block: 256 threads (4 waves), M-tile = 64 rows. H processed in 10 chunks of 64.
// LDS: Ab 64x168 bf16 (21.0KB) + Wb 64x168 (21.0KB) + Hb 64x72 (9.0KB)
//      + W2b 160x72 (22.5KB) = 73.5KB -> 2 blocks/CU.
__global__ __launch_bounds__(256) void mlp_mfma_kernel(
    float* io, const float* __restrict__ W1, const float* __restrict__ b1,
    const float* __restrict__ W2, const float* __restrict__ b2) {
  __shared__ short Ab[64 * 168];
  __shared__ short Wb[64 * 168];
  __shared__ short Hb[64 * 72];
  __shared__ short W2b[160 * 72];
  const int tid = threadIdx.x;
  const int lane = tid & 63;
  const int wv = tid >> 6;  // wave id 0..3 == M-tile
  const long long r0 = (long long)blockIdx.x * 64;

  // Stage Ab: FB tile 64x160 fp32 -> bf16 (rows k-contiguous, stride 168)
#pragma unroll
  for (int i = 0; i < 10; ++i) {
    const int idx = tid + i * 256;  // < 2560
    const int r = idx / 40, kq = idx % 40;
    const float4 v = *(const float4*)(io + (r0 + r) * Fn + kq * 4);
    *(ushort4*)&Ab[r * 168 + kq * 4] =
        make_ushort4(f2bf(v.x), f2bf(v.y), f2bf(v.z), f2bf(v.w));
  }
  __syncthreads();

  const int cl = lane & 15;         // frag col/row-in-tile index
  const int q8 = (lane >> 4) * 8;   // frag k offset
  const int ar = wv * 16 + cl;      // this wave's A rows
  // Hoist A fragments (Ab is never rewritten): 5 k-slices of 32
  bf16x8 afr[5];
#pragma unroll
  for (int kk = 0; kk < 5; ++kk)
    afr[kk] = *(const bf16x8*)&Ab[ar * 168 + kk * 32 + q8];

  f32x4 acc[10];
#pragma unroll
  for (int n = 0; n < 10; ++n) acc[n] = (f32x4){0.f, 0.f, 0.f, 0.f};

  for (int nc = 0; nc < 10; ++nc) {
    if (nc) __syncthreads();  // prior-iter Wb/W2b readers done
    // Stage Wb: W1 rows nc*64..+64 (k=0..160) -> bf16
#pragma unroll
    for (int i = 0; i < 10; ++i) {
      const int idx = tid + i * 256;
      const int r = idx / 40, kq = idx % 40;
      const float4 v = *(const float4*)(W1 + (nc * 64 + r) * Fn + kq * 4);
      *(ushort4*)&Wb[r * 168 + kq * 4] =
          make_ushort4(f2bf(v.x), f2bf(v.y), f2bf(v.z), f2bf(v.w));
    }
    // Stage W2b: W2[n][nc*64 + k], n=0..159, k=0..63 -> bf16 (rows k-contig)
#pragma unroll
    for (int i = 0; i < 10; ++i) {
      const int idx = tid + i * 256;
      const int n = idx >> 4, kq = idx & 15;
      const float4 v = *(const float4*)(W2 + n * 640 + nc * 64 + kq * 4);
      *(ushort4*)&W2b[n * 72 + kq * 4] =
          make_ushort4(f2bf(v.x), f2bf(v.y), f2bf(v.z), f2bf(v.w));
    }
    __syncthreads();
    // Phase 1: Hc[wave's 16 rows x 64 cols] = relu(A @ W1T + b1), 4 N-tiles
#pragma unroll
    for (int n16 = 0; n16 < 4; ++n16) {
      f32x4 hcc = (f32x4){0.f, 0.f, 0.f, 0.f};
      const int br = n16 * 16 + cl;
#pragma unroll
      for (int kk = 0; kk < 5; ++kk) {
        const bf16x8 bfr = *(const bf16x8*)&Wb[br * 168 + kk * 32 + q8];
        hcc = __builtin_amdgcn_mfma_f32_16x16x32_bf16(afr[kk], bfr, hcc, 0, 0, 0);
      }
      const float b1v = b1[nc * 64 + n16 * 16 + cl];
      const int hrow0 = wv * 16 + (lane >> 4) * 4;
      const int hcol = n16 * 16 + cl;
#pragma unroll
      for (int r = 0; r < 4; ++r)
        Hb[(hrow0 + r) * 72 + hcol] = f2bf(fmaxf(hcc[r] + b1v, 0.f));
    }
    // No barrier: wave reads back only its own Hb rows.
    bf16x8 a2[2];
#pragma unroll
    for (int kk = 0; kk < 2; ++kk)
      a2[kk] = *(const bf16x8*)&Hb[ar * 72 + kk * 32 + q8];
    // Phase 2: out[64x160] += Hc @ W2T  (10 N-tiles, K=64)
#pragma unroll
    for (int n16 = 0; n16 < 10; ++n16) {
      const int br = n16 * 16 + cl;
#pragma unroll
      for (int kk = 0; kk < 2; ++kk) {
        const bf16x8 b2f = *(const bf16x8*)&W2b[br * 72 + kk * 32 + q8];
        acc[n16] = __builtin_amdgcn_mfma_f32_16x16x32_bf16(a2[kk], b2f, acc[n16], 0, 0, 0);
      }
    }
  }
  // Epilogue: + b2, fp32 store
  const int orow0 = wv * 16 + (lane >> 4) * 4;
#pragma unroll
  for (int n16 = 0; n16 < 10; ++n16) {
    const float b2v = b2[n16 * 16 + cl];
#pragma unroll
    for (int r = 0; r < 4; ++r)
      io[(r0 + orow0 + r) * Fn + n16 * 16 + cl] = acc[n16][r] + b2v;
  }
}

extern "C" void kernel_launch(void* const* d_in, const int* in_sizes, int n_in,
                              void* d_out, int out_size, void* d_ws, size_t ws_size,
                              hipStream_t stream) {
  const float* x    = (const float*)d_in[0];
  const float* Wih0 = (const float*)d_in[1];
  const float* Whh0 = (const float*)d_in[2];
  const float* bih0 = (const float*)d_in[3];
  const float* bhh0 = (const float*)d_in[4];
  const float* Wih1 = (const float*)d_in[5];
  const float* Whh1 = (const float*)d_in[6];
  const float* bih1 = (const float*)d_in[7];
  const float* bhh1 = (const float*)d_in[8];
  const float* W1   = (const float*)d_in[9];
  const float* b1   = (const float*)d_in[10];
  const float* W2   = (const float*)d_in[11];
  const float* b2   = (const float*)d_in[12];
  float* out = (float*)d_out;
  (void)d_ws; (void)ws_size;

  // Both LSTM layers fused -> d_out = fullband (h1 + x)
  scan2_kernel<<<dim3(512), dim3(64), 0, stream>>>(
      x, Wih0, Whh0, bih0, bhh0, Wih1, Whh1, bih1, bhh1, out);
  // MFMA MLP in place on d_out
  mlp_mfma_kernel<<<dim3(NR / 64), dim3(256), 0, stream>>>(out, W1, b1, W2, b2);
}

// Round 4
// 1037.773 us; speedup vs baseline: 4.7544x; 1.6027x over previous
//
#include <hip/hip_runtime.h>

// SubLSTM: G=8, D=20, B=64, T=2000, F=160.
// R4: scan2p = two LSTM layers pipelined across 2 waves of one block
//     (wave0 produces h0 into an LDS ring; wave1 consumes with a 1-chunk skew,
//      adds x residual, writes fullband). One __syncthreads per 8-step chunk.
//     mlp_mfma unchanged from R3 (bf16 MFMA, ~210us).

#define Gn 8
#define Dn 20
#define Bn 64
#define Tn 2000
#define Fn 160
#define NR (Bn * Tn)
#define Kc 8    // steps per chunk
#define RING 16 // 2 chunks

__device__ __forceinline__ float fsigm(float x) {
  return __builtin_amdgcn_rcpf(1.f + __expf(-x));
}
__device__ __forceinline__ float ftanh(float x) {
  return 1.f - 2.f * __builtin_amdgcn_rcpf(__expf(2.f * x) + 1.f);
}
__device__ __forceinline__ float rdlane(float v, int k) {
  return __int_as_float(__builtin_amdgcn_readlane(__float_as_int(v), k));
}
__device__ __forceinline__ unsigned short f2bf(float f) {
  unsigned u = __float_as_uint(f);
  u += 0x8000u;
  return (unsigned short)(u >> 16);
}

// gA = gates[lane] (0..63), gB = gates[64+(lane&15)] (lanes 0..15 valid).
// Update lanes d=0..19: i=g[d], f=g[20+d], g=g[40+d], o=g[60+d].
__device__ __forceinline__ void lstm_update(float gA, float gB, int lane,
                                            float& h, float& c) {
  const float fg = __shfl(gA, (20 + lane) & 63);
  const float gg = __shfl(gA, (40 + lane) & 63);
  const float o1v = __shfl(gA, (60 + lane) & 63);
  const float o2v = __shfl(gB, (lane - 4) & 63);
  const float og = (lane < 4) ? o1v : o2v;
  const float sI = fsigm(gA);
  const float sF = fsigm(fg);
  const float sO = fsigm(og);
  const float tG = ftanh(gg);
  c = sF * c + sI * tG;
  h = sO * ftanh(c);
}

// One block (128 thr = 2 waves) per (g,b) chain; 512 blocks -> 1024 waves.
__global__ __launch_bounds__(128) void scan2p_kernel(
    const float* __restrict__ x, const float* __restrict__ Wih0,
    const float* __restrict__ Whh0, const float* __restrict__ bih0,
    const float* __restrict__ bhh0, const float* __restrict__ Wih1,
    const float* __restrict__ Whh1, const float* __restrict__ bih1,
    const float* __restrict__ bhh1, float* __restrict__ out) {
  __shared__ float hring[RING][20];  // h0 handoff ring (rows 80B -> float2-aligned)
  const int tid = threadIdx.x;
  const int lane = tid & 63;
  const int wv = tid >> 6;  // 0: layer0 producer, 1: layer1 consumer
  const int chain = blockIdx.x;
  const int g = chain >> 6;
  const int b = chain & 63;

  const float* Wg = (wv ? Whh1 : Whh0) + g * 1600;
  const float* Ug = (wv ? Wih1 : Wih0) + g * 1600;
  const float* bi = (wv ? bih1 : bih0) + g * 80;
  const float* bh = (wv ? bhh1 : bhh0) + g * 80;
  float WA[20], WB[20], UA[20], UB[20];
  {
    const int rB = 64 + (lane & 15);
#pragma unroll
    for (int k = 0; k < 20; ++k) {
      WA[k] = Wg[lane * 20 + k];
      WB[k] = Wg[rB * 20 + k];
      UA[k] = Ug[lane * 20 + k];
      UB[k] = Ug[rB * 20 + k];
    }
  }
  const float bsA = bi[lane] + bh[lane];
  const float bsB = bi[64 + (lane & 15)] + bh[64 + (lane & 15)];
  const bool wl = lane < Dn;
  const long long base = ((long long)b * Tn) * Fn + g * Dn + (wl ? lane : 0);
  const float* xp = x + base;   // wave0: layer0 input; wave1: residual
  float* outp = out + base;

  float px[Kc];
#pragma unroll
  for (int p = 0; p < Kc; ++p) px[p] = wl ? xp[(long long)p * Fn] : 0.f;

  float h = 0.f, c = 0.f;

  for (int cix = 0; cix <= 250; ++cix) {
    if (wv == 0) {
      if (cix < 250) {
#pragma unroll
        for (int p = 0; p < Kc; ++p) {
          const int t = cix * Kc + p;
          const float xv = px[p];
          {  // prefetch next chunk's x (clamped; clamped values never consumed)
            const int tp = min(t + Kc, Tn - 1);
            px[p] = wl ? xp[(long long)tp * Fn] : 0.f;
          }
          float aH0 = bsA, aH1 = 0.f, aX0 = 0.f, aX1 = 0.f;
          float bH0 = bsB, bH1 = 0.f, bX0 = 0.f, bX1 = 0.f;
#pragma unroll
          for (int k = 0; k < 20; k += 2) {
            const float hk0 = rdlane(h, k), hk1 = rdlane(h, k + 1);
            const float xk0 = rdlane(xv, k), xk1 = rdlane(xv, k + 1);
            aH0 += WA[k] * hk0;
            aH1 += WA[k + 1] * hk1;
            aX0 += UA[k] * xk0;
            aX1 += UA[k + 1] * xk1;
            bH0 += WB[k] * hk0;
            bH1 += WB[k + 1] * hk1;
            bX0 += UB[k] * xk0;
            bX1 += UB[k + 1] * xk1;
          }
          lstm_update((aH0 + aH1) + (aX0 + aX1), (bH0 + bH1) + (bX0 + bX1),
                      lane, h, c);
          if (wl) hring[t & (RING - 1)][lane] = h;
        }
      }
    } else {
      if (cix > 0) {
#pragma unroll
        for (int p = 0; p < Kc; ++p) {
          const int t = (cix - 1) * Kc + p;
          const float xv = px[p];  // residual x(t)
          {
            const int tp = min(t + Kc, Tn - 1);
            px[p] = wl ? xp[(long long)tp * Fn] : 0.f;
          }
          const float* hrow = hring[t & (RING - 1)];
          float aH0 = bsA, aH1 = 0.f, aX0 = 0.f, aX1 = 0.f;
          float bH0 = bsB, bH1 = 0.f, bX0 = 0.f, bX1 = 0.f;
#pragma unroll
          for (int k = 0; k < 20; k += 2) {
            const float2 hp = *(const float2*)&hrow[k];  // h0(t) broadcast (LDS pipe)
            const float hk0 = rdlane(h, k), hk1 = rdlane(h, k + 1);
            aH0 += WA[k] * hk0;
            aH1 += WA[k + 1] * hk1;
            aX0 += UA[k] * hp.x;
            aX1 += UA[k + 1] * hp.y;
            bH0 += WB[k] * hk0;
            bH1 += WB[k + 1] * hk1;
            bX0 += UB[k] * hp.x;
            bX1 += UB[k + 1] * hp.y;
          }
          lstm_update((aH0 + aH1) + (aX0 + aX1), (bH0 + bH1) + (bX0 + bX1),
                      lane, h, c);
          if (wl) outp[(long long)t * Fn] = h + xv;
        }
      }
    }
    __syncthreads();  // chunk boundary: ring half handoff
  }
}

// ---- MFMA bf16 MLP, in place on io[NR][160] (unchanged from R3) ----
typedef __attribute__((ext_vector_type(8))) short bf16x8;
typedef __attribute__((ext_vector_type(4))) float f32x4;

__global__ __launch_bounds__(256) void mlp_mfma_kernel(
    float* io, const float* __restrict__ W1, const float* __restrict__ b1,
    const float* __restrict__ W2, const float* __restrict__ b2) {
  __shared__ short Ab[64 * 168];
  __shared__ short Wb[64 * 168];
  __shared__ short Hb[64 * 72];
  __shared__ short W2b[160 * 72];
  const int tid = threadIdx.x;
  const int lane = tid & 63;
  const int wv = tid >> 6;
  const long long r0 = (long long)blockIdx.x * 64;

#pragma unroll
  for (int i = 0; i < 10; ++i) {
    const int idx = tid + i * 256;
    const int r = idx / 40, kq = idx % 40;
    const float4 v = *(const float4*)(io + (r0 + r) * Fn + kq * 4);
    *(ushort4*)&Ab[r * 168 + kq * 4] =
        make_ushort4(f2bf(v.x), f2bf(v.y), f2bf(v.z), f2bf(v.w));
  }
  __syncthreads();

  const int cl = lane & 15;
  const int q8 = (lane >> 4) * 8;
  const int ar = wv * 16 + cl;
  bf16x8 afr[5];
#pragma unroll
  for (int kk = 0; kk < 5; ++kk)
    afr[kk] = *(const bf16x8*)&Ab[ar * 168 + kk * 32 + q8];

  f32x4 acc[10];
#pragma unroll
  for (int n = 0; n < 10; ++n) acc[n] = (f32x4){0.f, 0.f, 0.f, 0.f};

  for (int nc = 0; nc < 10; ++nc) {
    if (nc) __syncthreads();
#pragma unroll
    for (int i = 0; i < 10; ++i) {
      const int idx = tid + i * 256;
      const int r = idx / 40, kq = idx % 40;
      const float4 v = *(const float4*)(W1 + (nc * 64 + r) * Fn + kq * 4);
      *(ushort4*)&Wb[r * 168 + kq * 4] =
          make_ushort4(f2bf(v.x), f2bf(v.y), f2bf(v.z), f2bf(v.w));
    }
#pragma unroll
    for (int i = 0; i < 10; ++i) {
      const int idx = tid + i * 256;
      const int n = idx >> 4, kq = idx & 15;
      const float4 v = *(const float4*)(W2 + n * 640 + nc * 64 + kq * 4);
      *(ushort4*)&W2b[n * 72 + kq * 4] =
          make_ushort4(f2bf(v.x), f2bf(v.y), f2bf(v.z), f2bf(v.w));
    }
    __syncthreads();
#pragma unroll
    for (int n16 = 0; n16 < 4; ++n16) {
      f32x4 hcc = (f32x4){0.f, 0.f, 0.f, 0.f};
      const int br = n16 * 16 + cl;
#pragma unroll
      for (int kk = 0; kk < 5; ++kk) {
        const bf16x8 bfr = *(const bf16x8*)&Wb[br * 168 + kk * 32 + q8];
        hcc = __builtin_amdgcn_mfma_f32_16x16x32_bf16(afr[kk], bfr, hcc, 0, 0, 0);
      }
      const float b1v = b1[nc * 64 + n16 * 16 + cl];
      const int hrow0 = wv * 16 + (lane >> 4) * 4;
      const int hcol = n16 * 16 + cl;
#pragma unroll
      for (int r = 0; r < 4; ++r)
        Hb[(hrow0 + r) * 72 + hcol] = f2bf(fmaxf(hcc[r] + b1v, 0.f));
    }
    bf16x8 a2[2];
#pragma unroll
    for (int kk = 0; kk < 2; ++kk)
      a2[kk] = *(const bf16x8*)&Hb[ar * 72 + kk * 32 + q8];
#pragma unroll
    for (int n16 = 0; n16 < 10; ++n16) {
      const int br = n16 * 16 + cl;
#pragma unroll
      for (int kk = 0; kk < 2; ++kk) {
        const bf16x8 b2f = *(const bf16x8*)&W2b[br * 72 + kk * 32 + q8];
        acc[n16] = __builtin_amdgcn_mfma_f32_16x16x32_bf16(a2[kk], b2f, acc[n16], 0, 0, 0);
      }
    }
  }
  const int orow0 = wv * 16 + (lane >> 4) * 4;
#pragma unroll
  for (int n16 = 0; n16 < 10; ++n16) {
    const float b2v = b2[n16 * 16 + cl];
#pragma unroll
    for (int r = 0; r < 4; ++r)
      io[(r0 + orow0 + r) * Fn + n16 * 16 + cl] = acc[n16][r] + b2v;
  }
}

extern "C" void kernel_launch(void* const* d_in, const int* in_sizes, int n_in,
                              void* d_out, int out_size, void* d_ws, size_t ws_size,
                              hipStream_t stream) {
  const float* x    = (const float*)d_in[0];
  const float* Wih0 = (const float*)d_in[1];
  const float* Whh0 = (const float*)d_in[2];
  const float* bih0 = (const float*)d_in[3];
  const float* bhh0 = (const float*)d_in[4];
  const float* Wih1 = (const float*)d_in[5];
  const float* Whh1 = (const float*)d_in[6];
  const float* bih1 = (const float*)d_in[7];
  const float* bhh1 = (const float*)d_in[8];
  const float* W1   = (const float*)d_in[9];
  const float* b1   = (const float*)d_in[10];
  const float* W2   = (const float*)d_in[11];
  const float* b2   = (const float*)d_in[12];
  float* out = (float*)d_out;
  (void)d_ws; (void)ws_size;

  scan2p_kernel<<<dim3(512), dim3(128), 0, stream>>>(
      x, Wih0, Whh0, bih0, bhh0, Wih1, Whh1, bih1, bhh1, out);
  mlp_mfma_kernel<<<dim3(NR / 64), dim3(256), 0, stream>>>(out, W1, b1, W2, b2);
}